// Round 16
// baseline (318.942 us; speedup 1.0000x reference)
//
#include <hip/hip_runtime.h>

typedef float    f32x4 __attribute__((ext_vector_type(4)));
typedef int      i32x4 __attribute__((ext_vector_type(4)));
typedef unsigned u32x4 __attribute__((ext_vector_type(4)));

typedef const __attribute__((address_space(1))) void* gptr_t;
typedef __attribute__((address_space(3))) void* lptr_t;

__device__ __forceinline__ void gload_lds16(const void* g, void* l) {
  __builtin_amdgcn_global_load_lds((gptr_t)g, (lptr_t)l, 16, 0, 0);
}

constexpr int Bsz  = 8192;
constexpr int Nin  = 128;
constexpr int Hd   = 1024;
constexpr int Aact = 32;
constexpr int Od   = 64;
constexpr int KC = 384;           // OpenBLAS K-block (R10-validated)
constexpr float DELTA = 1.5e-4f;  // 3-plane: np-window + trunc, validated R6-R15
constexpr unsigned WCAP = 262144;

// i32 plane-combine scale: G = (float)s * 2^-23, s = (S0<<14)+(S1<<7)+S2.
// |S0| <= 86*1024 -> |s| <= 1.48e9 < 2^31. (float)s * 2^-23f rounds the same
// exact real as the old double path -> identical bits (R12-validated).
constexpr float CSCALE = 1.1920928955078125e-7f;   // 2^-23

// ======================================================================
// PREP: one kernel, two block roles (R13-validated: x1 in two K=64 halves,
// 34.8 KB LDS -> 4 blocks/CU).
// ======================================================================
__global__ __launch_bounds__(256)
void prep_kernel(const float* __restrict__ state, const float* __restrict__ w1,
                 const float* __restrict__ b1,
                 const float* __restrict__ w2, const float* __restrict__ w3,
                 unsigned char* __restrict__ s1pack,
                 char* __restrict__ p1, char* __restrict__ p2, char* __restrict__ p3,
                 char* __restrict__ r1, char* __restrict__ r2, char* __restrict__ r3,
                 float* __restrict__ w2tf, unsigned* __restrict__ wcnt) {
  __shared__ float sAT[64][68];        // 17.4 KB (k-half rows, rotated transpose)
  __shared__ float sB[64][68];         // 17.4 KB
  const int tid = threadIdx.x;

  if (blockIdx.x >= 2048) {            // ---- wsplit role (R11/R12-validated)
    if (blockIdx.x == 2048 && tid < 8) wcnt[tid] = 0;
    const int u = (blockIdx.x - 2048) * 4 + (tid >> 6);   // 0..1087
    const int lane = tid & 63;
    const int l15 = lane & 15, quad = lane >> 4;
    const int pn = u >> 4;             // 0..63 = w2 panels, 64..67 = w3
    const int kb = u & 15;
    const bool isw3 = (pn >= Hd / 16);
    const int pnl = isw3 ? pn - Hd / 16 : pn;
    const float* src = isw3 ? w3 : w2;
    const int N = isw3 ? Od : Hd;
    const int n = pnl * 16 + l15;
    const int k0 = kb * 64 + quad * 16;
    char* d1 = isw3 ? r1 : p1;
    char* d2 = isw3 ? r2 : p2;
    char* d3 = isw3 ? r3 : p3;
    float wv[16];
    char o1[16], o2[16], o3[16];
#pragma unroll
    for (int e = 0; e < 16; ++e) {
      float w = src[(size_t)(k0 + e) * N + n];
      wv[e] = w;
      float m1 = rintf(w * 512.0f);
      float q1 = w - m1 * (1.0f / 512.0f);            // exact
      float m2 = rintf(q1 * 65536.0f);
      float q2 = q1 - m2 * (1.0f / 65536.0f);         // exact
      float m3 = rintf(q2 * 8388608.0f);              // 2^23
      o1[e] = (char)(int)m1; o2[e] = (char)(int)m2; o3[e] = (char)(int)m3;
    }
    size_t off = ((size_t)pnl * 16 + kb) * 1024 + (size_t)lane * 16;
#pragma unroll
    for (int e = 0; e < 16; ++e) {
      d1[off + e] = o1[e]; d2[off + e] = o2[e]; d3[off + e] = o3[e];
    }
    if (!isw3) {                       // fused transpose: w2tf[n][k] = w2[k][n]
#pragma unroll
      for (int e = 0; e < 16; ++e)
        w2tf[(size_t)n * Hd + k0 + e] = wv[e];
    }
    return;
  }

  // ---- x1 role (two K=64 halves, R13-validated)
  const int m0 = (blockIdx.x & 127) * 64, n0 = (blockIdx.x >> 7) * 64;
  const int tx = tid & 15, ty = tid >> 4;
  float acc[4][4] = {};
#pragma unroll
  for (int h = 0; h < 2; ++h) {
    if (h) __syncthreads();            // half-0 reads complete before overwrite
    for (int idx = tid; idx < 1024; idx += 256) {   // state 64 rows x 64 cols
      int r = idx >> 4, c4 = (idx & 15) << 2;
      float4 v = *(const float4*)(state + (size_t)(m0 + r) * Nin + h * 64 + c4);
      int pc = (r + c4) & 63;          // rotation, h-invariant
      sAT[c4 + 0][pc] = v.x; sAT[c4 + 1][pc] = v.y;
      sAT[c4 + 2][pc] = v.z; sAT[c4 + 3][pc] = v.w;
    }
    for (int idx = tid; idx < 1024; idx += 256) {   // w1 64 rows x 64 cols
      int r = idx >> 4, c4 = (idx & 15) << 2;
      *(float4*)&sB[r][c4] = *(const float4*)(w1 + (size_t)(h * 64 + r) * Hd + n0 + c4);
    }
    __syncthreads();
    for (int k = 0; k < 64; ++k) {     // ASCENDING global k: np order preserved
      int cb = ((ty << 2) + (k & ~3)) & 63;
      float4 a4 = *(const float4*)&sAT[k][cb];   // broadcast, 16B-aligned
      float4 b = *(const float4*)&sB[k][tx * 4];
      float a[4] = {a4.x, a4.y, a4.z, a4.w};
#pragma unroll
      for (int i = 0; i < 4; ++i) {
        acc[i][0] = __fmaf_rn(a[i], b.x, acc[i][0]);
        acc[i][1] = __fmaf_rn(a[i], b.y, acc[i][1]);
        acc[i][2] = __fmaf_rn(a[i], b.z, acc[i][2]);
        acc[i][3] = __fmaf_rn(a[i], b.w, acc[i][3]);
      }
    }
  }
#pragma unroll
  for (int i = 0; i < 4; ++i) {
    int m = m0 + ty * 4 + i;
    unsigned pack = 0;
#pragma unroll
    for (int j = 0; j < 4; ++j) {
      int n = n0 + tx * 4 + j;
      float x = acc[i][j];
      float bb = b1[n];
      float v = 0.0f;
      unsigned bits = 0;
#pragma unroll
      for (int t = 0; t < 8; ++t) {
        float h2 = __fadd_rn(__fadd_rn(v, x), bb);  // np: (v1 + G1) + b1
        if (h2 >= 1.0f) { bits |= (1u << t); v = 0.0f; } else { v = h2; }
      }
      pack |= bits << (8 * j);
    }
    *(unsigned*)(s1pack + (size_t)m * Hd + n0 + tx * 4) = pack;
  }
}

// ======================================================================
// GEMM2 — R16: t-batch SPLIT ACROSS WAVES. 8 waves/block; waves w and w+4
// cover the same 16 rows, each owning 4 timesteps -> acc[3][4] = 48 AGPR
// (was 96) -> __launch_bounds__(512,4) targets 4 waves/SIMD (was 2.6).
// After the K-loop each wave combines its G[t] into sG (LDS), one barrier,
// then 1024 sites redistribute 2/thread for the sequential v2 recurrence.
// G values bit-identical (same exact i32 accs, same R12 combine); the
// recurrence fp32 op order is unchanged -> outputs identical.
// Staging: waves 0-3 stage A, waves 4-6 stage B planes, wave 7 idle;
// 1 load/wave/stage -> counted vmcnt(1) (stage kb is 2 iters old).
// ======================================================================
__global__ __launch_bounds__(512, 4)
void gemm2i8_kernel(const unsigned char* __restrict__ s1pack,
                    const char* __restrict__ q1, const char* __restrict__ q2,
                    const char* __restrict__ q3,
                    const float* __restrict__ b2,
                    unsigned char* __restrict__ s2p,
                    unsigned* __restrict__ wcnt, unsigned* __restrict__ wlist) {
  constexpr int NKB = Hd / 64;         // 16 K-steps
  __shared__ __align__(16) unsigned char lA[3][64 * 64];  // 12 KB
  __shared__ __align__(16) char lB[3][3072];              // 9 KB
  __shared__ float sG[64][145];        // 37 KB: [row][col*9 + t], padded banks
  const int tid = threadIdx.x;
  const int m0 = blockIdx.x * 64;
  const int n0 = blockIdx.y * 16;
  const int wave = tid >> 6, lane = tid & 63, l15 = lane & 15, quad = lane >> 4;
  const int wrow = wave & 3;           // row-group
  const int wt4 = (wave >> 2) << 2;    // t-base: 0 or 4
  // staging sources
  const unsigned char* asrc = s1pack
      + (size_t)(m0 + ((tid >> 6) << 4) + (tid & 15)) * Hd + ((tid >> 4) & 3) * 16;
  const char* bplane = (wave == 4) ? q1 : (wave == 5) ? q2 : q3;
  const char* bsrc2 = bplane + (size_t)blockIdx.y * NKB * 1024 + (size_t)lane * 16;
  i32x4 acc[3][4] = {};                // [plane][tt], 48 AGPR
  unsigned msk[4];                     // loop-invariant expansion masks
#pragma unroll
  for (int tt = 0; tt < 4; ++tt) msk[tt] = 0x01010101u << (wt4 + tt);

  auto stage = [&](int kb, int buf) {
    if (wave < 4)
      gload_lds16(asrc + kb * 64, &lA[buf][tid * 16]);     // tid*16 = wave*1024+lane*16
    else if (wave < 7)
      gload_lds16(bsrc2 + (size_t)kb * 1024, &lB[buf][(wave - 4) * 1024 + lane * 16]);
  };
  stage(0, 0); stage(1, 1);

#pragma unroll
  for (int kb = 0; kb < NKB; ++kb) {
    const int cur = kb % 3;
    if (kb < NKB - 1) {                // stage(kb) is 2 iters old -> free wait
      asm volatile("s_waitcnt vmcnt(1)" ::: "memory");   // 1 load/stage; wave7: trivially 0
    } else {
      asm volatile("s_waitcnt vmcnt(0)" ::: "memory");
    }
    __builtin_amdgcn_s_barrier();
    asm volatile("" ::: "memory");     // no LDS ops cross the barrier
    u32x4 ad = *(const u32x4*)&lA[cur][wrow * 1024 + lane * 16];
    i32x4 fb0 = *(const i32x4*)&lB[cur][lane * 16];
    i32x4 fb1 = *(const i32x4*)&lB[cur][1024 + lane * 16];
    i32x4 fb2 = *(const i32x4*)&lB[cur][2048 + lane * 16];
    if (kb + 2 < NKB) stage(kb + 2, (kb + 2) % 3);
#pragma unroll
    for (int tt = 0; tt < 4; ++tt) {   // masked expansion: A bytes {0, 2^t}
      i32x4 af;
      af[0] = (int)(ad[0] & msk[tt]);
      af[1] = (int)(ad[1] & msk[tt]);
      af[2] = (int)(ad[2] & msk[tt]);
      af[3] = (int)(ad[3] & msk[tt]);
      acc[0][tt] = __builtin_amdgcn_mfma_i32_16x16x64_i8(af, fb0, acc[0][tt], 0, 0, 0);
      acc[1][tt] = __builtin_amdgcn_mfma_i32_16x16x64_i8(af, fb1, acc[1][tt], 0, 0, 0);
      acc[2][tt] = __builtin_amdgcn_mfma_i32_16x16x64_i8(af, fb2, acc[2][tt], 0, 0, 0);
    }
  }
  // combine this wave's 4 timesteps -> sG (exact i32 combine, R12-validated;
  // t=7: acc = -2^7*sum, (acc>>7) = -sum exactly, sign restored via -CSCALE)
#pragma unroll
  for (int r = 0; r < 4; ++r) {
    int row = wrow * 16 + quad * 4 + r;
#pragma unroll
    for (int tt = 0; tt < 4; ++tt) {
      int t = wt4 + tt;
      int a0 = acc[0][tt][r] >> t;
      int a1 = acc[1][tt][r] >> t;
      int a2 = acc[2][tt][r] >> t;
      int s = (a0 << 14) + (a1 << 7) + a2;   // |s| <= 1.48e9 < 2^31
      sG[row][l15 * 9 + t] = (float)s * ((t == 7) ? -CSCALE : CSCALE);
    }
  }
  __syncthreads();
  // v2 recurrence: 1024 sites, 2 per thread (same fp32 op order as validated)
#pragma unroll
  for (int ss = 0; ss < 2; ++ss) {
    int site = tid + ss * 512;
    int row = site >> 4, col = site & 15;
    const float* Gp = &sG[row][col * 9];
    float bb = b2[n0 + col];
    size_t idx = (size_t)(m0 + row) * Hd + (n0 + col);
    float v = 0.0f;
    unsigned bits = 0;
#pragma unroll
    for (int t = 0; t < 8; ++t) {
      float h = __fadd_rn(__fadd_rn(v, Gp[t]), bb);  // np: (v2 + G) + b2
      if (__builtin_expect(__builtin_fabsf(h - 1.0f) < DELTA, 0)) {
        unsigned pos = atomicAdd(wcnt, 1u);          // fixup rewrites ALL 8 bits
        if (pos < WCAP) wlist[pos] = (unsigned)idx;
      }
      bool sp = (h >= 1.0f);
      if (sp) bits |= (1u << t);
      v = sp ? 0.0f : h;
    }
    s2p[idx] = (unsigned char)bits;
  }
}

// ---- fixup: replay np's v2 recursion for worklist sites (3 lanes/site, one
// per KC block; branchless ascending adds; np fold (S1+S2)+S3) — validated.
__global__ __launch_bounds__(256)
void fixup_kernel(const unsigned* __restrict__ wcnt, const unsigned* __restrict__ wlist,
                  const unsigned char* __restrict__ s1pack, const float* __restrict__ w2tf,
                  const float* __restrict__ b2, unsigned char* __restrict__ s2p) {
  unsigned cnt = *wcnt;
  if (cnt > WCAP) cnt = WCAP;
  const int tid = threadIdx.x;
  const int lane = tid & 63;
  const int sl = lane / 3, blk3 = lane - sl * 3;
  const int wid = blockIdx.x * (blockDim.x >> 6) + (tid >> 6);
  const int nwaves = gridDim.x * (blockDim.x >> 6);
  for (unsigned base = (unsigned)wid * 21u; base < cnt; base += (unsigned)nwaves * 21u) {
    unsigned site = base + (unsigned)sl;
    bool act = (sl < 21) && (site < cnt);
    unsigned idx = act ? wlist[site] : 0u;
    int m = (int)(idx >> 10), n = (int)(idx & 1023u);
    const unsigned char* prow = s1pack + ((size_t)m << 10);
    const float* col = w2tf + ((size_t)n << 10);
    int kb = blk3 * KC;
    int kend = (blk3 == 2) ? Hd : kb + KC;
    float S[8] = {};
    if (act) {
      for (int k = kb; k < kend; k += 8) {
        float4 wa = *(const float4*)(col + k);
        float4 wb = *(const float4*)(col + k + 4);
        unsigned b0 = *(const unsigned*)(prow + k);
        unsigned b1 = *(const unsigned*)(prow + k + 4);
#pragma unroll
        for (int tau = 0; tau < 8; ++tau) {
          S[tau] = __fadd_rn(S[tau], ((b0 >> tau) & 1)        ? wa.x : 0.0f);
          S[tau] = __fadd_rn(S[tau], ((b0 >> (8 + tau)) & 1)  ? wa.y : 0.0f);
          S[tau] = __fadd_rn(S[tau], ((b0 >> (16 + tau)) & 1) ? wa.z : 0.0f);
          S[tau] = __fadd_rn(S[tau], ((b0 >> (24 + tau)) & 1) ? wa.w : 0.0f);
          S[tau] = __fadd_rn(S[tau], ((b1 >> tau) & 1)        ? wb.x : 0.0f);
          S[tau] = __fadd_rn(S[tau], ((b1 >> (8 + tau)) & 1)  ? wb.y : 0.0f);
          S[tau] = __fadd_rn(S[tau], ((b1 >> (16 + tau)) & 1) ? wb.z : 0.0f);
          S[tau] = __fadd_rn(S[tau], ((b1 >> (24 + tau)) & 1) ? wb.w : 0.0f);
        }
      }
    }
    float G[8];
#pragma unroll
    for (int tau = 0; tau < 8; ++tau) {
      float sB = __shfl(S[tau], lane + 1);
      float sC = __shfl(S[tau], lane + 2);
      G[tau] = __fadd_rn(__fadd_rn(S[tau], sB), sC);
    }
    if (act && blk3 == 0) {
      float bb = b2[n];
      float v = 0.0f;
      unsigned bits = 0;
      for (int tau = 0; tau < 8; ++tau) {
        float h = __fadd_rn(__fadd_rn(v, G[tau]), bb);
        bool sp = (h >= 1.0f);
        if (sp) bits |= (1u << tau);
        v = sp ? 0.0f : h;
      }
      s2p[idx] = (unsigned char)bits;
    }
  }
}

// ======================================================================
// GEMM3 + FINAL fused (R11/R12-validated). Untouched.
// ======================================================================
__global__ __launch_bounds__(256, 3)
void gemm3f_kernel(const unsigned char* __restrict__ s2p,
                   const char* __restrict__ q1, const char* __restrict__ q2,
                   const char* __restrict__ q3,
                   const float* __restrict__ b3, const float* __restrict__ eps,
                   float* __restrict__ action, float* __restrict__ logp) {
  constexpr int NKB = Hd / 64;
  __shared__ float sv[16][65];
  const int tid = threadIdx.x;
  const int m0 = blockIdx.x * 16;
  const int wave = tid >> 6, lane = tid & 63, l15 = lane & 15, quad = lane >> 4;
  const unsigned char* asrc = s2p + (size_t)(m0 + l15) * Hd + (lane >> 4) * 16;
  const size_t boff = (size_t)wave * NKB * 1024 + (size_t)lane * 16;
  const char* bp0 = q1 + boff;
  const char* bp1 = q2 + boff;
  const char* bp2 = q3 + boff;
  i32x4 acc[3][8] = {};

  u32x4 a_cur = *(const u32x4*)asrc;
  i32x4 f0c = *(const i32x4*)bp0;
  i32x4 f1c = *(const i32x4*)bp1;
  i32x4 f2c = *(const i32x4*)bp2;
#pragma unroll
  for (int kb = 0; kb < NKB; ++kb) {
    u32x4 a_nxt = a_cur; i32x4 f0n = f0c, f1n = f1c, f2n = f2c;
    if (kb + 1 < NKB) {
      a_nxt = *(const u32x4*)(asrc + (kb + 1) * 64);
      f0n = *(const i32x4*)(bp0 + (size_t)(kb + 1) * 1024);
      f1n = *(const i32x4*)(bp1 + (size_t)(kb + 1) * 1024);
      f2n = *(const i32x4*)(bp2 + (size_t)(kb + 1) * 1024);
    }
#pragma unroll
    for (int t = 0; t < 8; ++t) {
      const unsigned msk = 0x01010101u << t;
      i32x4 af;
      af[0] = (int)(a_cur[0] & msk);
      af[1] = (int)(a_cur[1] & msk);
      af[2] = (int)(a_cur[2] & msk);
      af[3] = (int)(a_cur[3] & msk);
      acc[0][t] = __builtin_amdgcn_mfma_i32_16x16x64_i8(af, f0c, acc[0][t], 0, 0, 0);
      acc[1][t] = __builtin_amdgcn_mfma_i32_16x16x64_i8(af, f1c, acc[1][t], 0, 0, 0);
      acc[2][t] = __builtin_amdgcn_mfma_i32_16x16x64_i8(af, f2c, acc[2][t], 0, 0, 0);
    }
    a_cur = a_nxt; f0c = f0n; f1c = f1n; f2c = f2n;
  }
  // LIF v3 epilogue -> LDS tile (i32 combine, rounding-identical)
  const int n = wave * 16 + l15;       // 0..63
  const float bb = b3[n];
#pragma unroll
  for (int r = 0; r < 4; ++r) {
    int row = quad * 4 + r;            // 0..15
    float v = 0.0f;
#pragma unroll
    for (int t = 0; t < 8; ++t) {
      int a0 = acc[0][t][r] >> t;
      int a1 = acc[1][t][r] >> t;
      int a2 = acc[2][t][r] >> t;
      int s = (a0 << 14) + (a1 << 7) + a2;
      float ge = (float)s * ((t == 7) ? -CSCALE : CSCALE);
      float x3 = __fadd_rn(ge, bb);           // same op order as validated
      float dd = __fsub_rn(x3, v);
      v = __fadd_rn(v, __fmul_rn(dd, 0.5f));
    }
    sv[row][n] = v;
  }
  __syncthreads();
  // final math (identical fp32/double sequence as validated final_kernel)
#pragma unroll
  for (int pass = 0; pass < 2; ++pass) {
    int row = (pass << 3) + (tid >> 5);  // 0..15
    int j = tid & 31;
    float mu = sv[row][j];
    float ls = sv[row][32 + j];
    ls = fminf(fmaxf(ls, -20.0f), 2.0f);
    float sd = (float)exp((double)ls);
    float e  = eps[(size_t)(m0 + row) * Aact + j];
    float z  = __fadd_rn(mu, __fmul_rn(sd, e));
    float a;
    if (__builtin_fabsf(z) >= 7.90531111f) a = __builtin_copysignf(1.0f, z);
    else                                   a = (float)tanh((double)z);
    float aa = __fmul_rn(a, a);
    float u  = __fadd_rn(__fsub_rn(1.0f, aa), 1e-7f);
    float lg = (float)log((double)u);
    float l  = __fmul_rn(__fmul_rn(-0.5f, e), e);
    l = __fsub_rn(l, ls);
    l = __fsub_rn(l, 0.9189385332046727f);
    float term = __fsub_rn(l, lg);
    action[(size_t)(m0 + row) * Aact + j] = a;
    double lp = (double)term;
#pragma unroll
    for (int w = 16; w >= 1; w >>= 1) lp += __shfl_xor(lp, w);
    if (j == 0) logp[m0 + row] = (float)lp;
  }
}

extern "C" void kernel_launch(void* const* d_in, const int* in_sizes, int n_in,
                              void* d_out, int out_size, void* d_ws, size_t ws_size,
                              hipStream_t stream) {
  const float* state = (const float*)d_in[0];
  const float* w1 = (const float*)d_in[1];
  const float* b1 = (const float*)d_in[2];
  const float* w2 = (const float*)d_in[3];
  const float* b2 = (const float*)d_in[4];
  const float* w3 = (const float*)d_in[5];
  const float* b3 = (const float*)d_in[6];
  const float* eps = (const float*)d_in[7];
  float* out_action = (float*)d_out;
  float* out_logp = out_action + (size_t)Bsz * Aact;

  char* p = (char*)d_ws;
  auto take = [&](size_t bytes) {
    char* r = p;
    p += (bytes + 255) & ~(size_t)255;
    return r;
  };
  unsigned char* s1pack = (unsigned char*)take((size_t)Bsz * Hd);  // 8 MB
  unsigned char* s2p = (unsigned char*)take((size_t)Bsz * Hd);     // 8 MB (bit-packed)
  char* w2q1 = (char*)take((size_t)Hd * Hd);                       // 1 MB x3 i8 planes
  char* w2q2 = (char*)take((size_t)Hd * Hd);
  char* w2q3 = (char*)take((size_t)Hd * Hd);
  char* w3q1 = (char*)take((size_t)Hd * Od);                       // 64 KB x3
  char* w3q2 = (char*)take((size_t)Hd * Od);
  char* w3q3 = (char*)take((size_t)Hd * Od);
  float* w2tf = (float*)take((size_t)Hd * Hd * 4);                 // 4 MB
  unsigned* wcnt = (unsigned*)take(8 * 4);
  unsigned* wlist = (unsigned*)take((size_t)WCAP * 4);             // 1 MB

  prep_kernel<<<2048 + 272, 256, 0, stream>>>(state, w1, b1, w2, w3, s1pack,
                                              w2q1, w2q2, w2q3, w3q1, w3q2, w3q3,
                                              w2tf, wcnt);
  gemm2i8_kernel<<<dim3(Bsz / 64, Hd / 16), 512, 0, stream>>>(s1pack, w2q1, w2q2, w2q3,
                                                              b2, s2p, wcnt, wlist);
  fixup_kernel<<<256, 256, 0, stream>>>(wcnt, wlist, s1pack, w2tf, b2, s2p);

  gemm3f_kernel<<<Bsz / 16, 256, 0, stream>>>(s2p, w3q1, w3q2, w3q3, b3, eps,
                                              out_action, out_logp);
}

// Round 17
// 287.198 us; speedup vs baseline: 1.1105x; 1.1105x over previous
//
#include <hip/hip_runtime.h>

typedef float    f32x4 __attribute__((ext_vector_type(4)));
typedef int      i32x4 __attribute__((ext_vector_type(4)));
typedef unsigned u32x4 __attribute__((ext_vector_type(4)));

typedef const __attribute__((address_space(1))) void* gptr_t;
typedef __attribute__((address_space(3))) void* lptr_t;

__device__ __forceinline__ void gload_lds16(const void* g, void* l) {
  __builtin_amdgcn_global_load_lds((gptr_t)g, (lptr_t)l, 16, 0, 0);
}

constexpr int Bsz  = 8192;
constexpr int Nin  = 128;
constexpr int Hd   = 1024;
constexpr int Aact = 32;
constexpr int Od   = 64;
constexpr int KC = 384;           // OpenBLAS K-block (R10-validated)
constexpr float DELTA = 1.5e-4f;  // 3-plane: np-window + trunc, validated R6-R15
constexpr unsigned WCAP = 262144;

// i32 plane-combine scale: G = (float)s * 2^-23, s = (S0<<14)+(S1<<7)+S2.
// |S0| <= 86*1024 -> |s| <= 1.48e9 < 2^31. (float)s * 2^-23f rounds the same
// exact real as the old double path -> identical bits (R12-validated).
constexpr float CSCALE = 1.1920928955078125e-7f;   // 2^-23

// ======================================================================
// PREP: one kernel, two block roles (R13-validated: x1 in two K=64 halves,
// 34.8 KB LDS -> 4 blocks/CU).
// ======================================================================
__global__ __launch_bounds__(256)
void prep_kernel(const float* __restrict__ state, const float* __restrict__ w1,
                 const float* __restrict__ b1,
                 const float* __restrict__ w2, const float* __restrict__ w3,
                 unsigned char* __restrict__ s1pack,
                 char* __restrict__ p1, char* __restrict__ p2, char* __restrict__ p3,
                 char* __restrict__ r1, char* __restrict__ r2, char* __restrict__ r3,
                 float* __restrict__ w2tf, unsigned* __restrict__ wcnt) {
  __shared__ float sAT[64][68];        // 17.4 KB (k-half rows, rotated transpose)
  __shared__ float sB[64][68];         // 17.4 KB
  const int tid = threadIdx.x;

  if (blockIdx.x >= 2048) {            // ---- wsplit role (R11/R12-validated)
    if (blockIdx.x == 2048 && tid < 8) wcnt[tid] = 0;
    const int u = (blockIdx.x - 2048) * 4 + (tid >> 6);   // 0..1087
    const int lane = tid & 63;
    const int l15 = lane & 15, quad = lane >> 4;
    const int pn = u >> 4;             // 0..63 = w2 panels, 64..67 = w3
    const int kb = u & 15;
    const bool isw3 = (pn >= Hd / 16);
    const int pnl = isw3 ? pn - Hd / 16 : pn;
    const float* src = isw3 ? w3 : w2;
    const int N = isw3 ? Od : Hd;
    const int n = pnl * 16 + l15;
    const int k0 = kb * 64 + quad * 16;
    char* d1 = isw3 ? r1 : p1;
    char* d2 = isw3 ? r2 : p2;
    char* d3 = isw3 ? r3 : p3;
    float wv[16];
    char o1[16], o2[16], o3[16];
#pragma unroll
    for (int e = 0; e < 16; ++e) {
      float w = src[(size_t)(k0 + e) * N + n];
      wv[e] = w;
      float m1 = rintf(w * 512.0f);
      float q1 = w - m1 * (1.0f / 512.0f);            // exact
      float m2 = rintf(q1 * 65536.0f);
      float q2 = q1 - m2 * (1.0f / 65536.0f);         // exact
      float m3 = rintf(q2 * 8388608.0f);              // 2^23
      o1[e] = (char)(int)m1; o2[e] = (char)(int)m2; o3[e] = (char)(int)m3;
    }
    size_t off = ((size_t)pnl * 16 + kb) * 1024 + (size_t)lane * 16;
#pragma unroll
    for (int e = 0; e < 16; ++e) {
      d1[off + e] = o1[e]; d2[off + e] = o2[e]; d3[off + e] = o3[e];
    }
    if (!isw3) {                       // fused transpose: w2tf[n][k] = w2[k][n]
#pragma unroll
      for (int e = 0; e < 16; ++e)
        w2tf[(size_t)n * Hd + k0 + e] = wv[e];
    }
    return;
  }

  // ---- x1 role (two K=64 halves, R13-validated)
  const int m0 = (blockIdx.x & 127) * 64, n0 = (blockIdx.x >> 7) * 64;
  const int tx = tid & 15, ty = tid >> 4;
  float acc[4][4] = {};
#pragma unroll
  for (int h = 0; h < 2; ++h) {
    if (h) __syncthreads();            // half-0 reads complete before overwrite
    for (int idx = tid; idx < 1024; idx += 256) {   // state 64 rows x 64 cols
      int r = idx >> 4, c4 = (idx & 15) << 2;
      float4 v = *(const float4*)(state + (size_t)(m0 + r) * Nin + h * 64 + c4);
      int pc = (r + c4) & 63;          // rotation, h-invariant
      sAT[c4 + 0][pc] = v.x; sAT[c4 + 1][pc] = v.y;
      sAT[c4 + 2][pc] = v.z; sAT[c4 + 3][pc] = v.w;
    }
    for (int idx = tid; idx < 1024; idx += 256) {   // w1 64 rows x 64 cols
      int r = idx >> 4, c4 = (idx & 15) << 2;
      *(float4*)&sB[r][c4] = *(const float4*)(w1 + (size_t)(h * 64 + r) * Hd + n0 + c4);
    }
    __syncthreads();
    for (int k = 0; k < 64; ++k) {     // ASCENDING global k: np order preserved
      int cb = ((ty << 2) + (k & ~3)) & 63;
      float4 a4 = *(const float4*)&sAT[k][cb];   // broadcast, 16B-aligned
      float4 b = *(const float4*)&sB[k][tx * 4];
      float a[4] = {a4.x, a4.y, a4.z, a4.w};
#pragma unroll
      for (int i = 0; i < 4; ++i) {
        acc[i][0] = __fmaf_rn(a[i], b.x, acc[i][0]);
        acc[i][1] = __fmaf_rn(a[i], b.y, acc[i][1]);
        acc[i][2] = __fmaf_rn(a[i], b.z, acc[i][2]);
        acc[i][3] = __fmaf_rn(a[i], b.w, acc[i][3]);
      }
    }
  }
#pragma unroll
  for (int i = 0; i < 4; ++i) {
    int m = m0 + ty * 4 + i;
    unsigned pack = 0;
#pragma unroll
    for (int j = 0; j < 4; ++j) {
      int n = n0 + tx * 4 + j;
      float x = acc[i][j];
      float bb = b1[n];
      float v = 0.0f;
      unsigned bits = 0;
#pragma unroll
      for (int t = 0; t < 8; ++t) {
        float h2 = __fadd_rn(__fadd_rn(v, x), bb);  // np: (v1 + G1) + b1
        if (h2 >= 1.0f) { bits |= (1u << t); v = 0.0f; } else { v = h2; }
      }
      pack |= bits << (8 * j);
    }
    *(unsigned*)(s1pack + (size_t)m * Hd + n0 + tx * 4) = pack;
  }
}

// ======================================================================
// GEMM2 — R12/R13 t-outer form (validated session best: ~156 us, MfmaUtil
// ~57%). Ledger of measured-worse restructures: counted-vmcnt deep (null),
// 2-tile phases (-4%), no-LDS (null), setprio (-5%), plane-outer (-37%,
// spills), wave-split t-batch (-9%, barrier amortization halved). The
// 96-AGPR t-batch floor at 24 MFMA/barrier is the measured optimum.
// ======================================================================
__global__ __launch_bounds__(256, 3)
void gemm2i8_kernel(const unsigned char* __restrict__ s1pack,
                    const char* __restrict__ q1, const char* __restrict__ q2,
                    const char* __restrict__ q3,
                    const float* __restrict__ b2,
                    unsigned char* __restrict__ s2p,
                    unsigned* __restrict__ wcnt, unsigned* __restrict__ wlist) {
  constexpr int NKB = Hd / 64;         // 16 K-steps
  __shared__ __align__(16) unsigned char lA[3][64 * 64];  // 12 KB
  __shared__ __align__(16) char lB[3][3072];              // 9 KB
  const int tid = threadIdx.x;
  const int m0 = blockIdx.x * 64;
  const int n0 = blockIdx.y * 16;
  const int wave = tid >> 6, lane = tid & 63, l15 = lane & 15, quad = lane >> 4;
  const char* bplane = (wave == 0) ? q1 : (wave == 1) ? q2 : q3;
  const unsigned char* asrc = s1pack
      + (size_t)(m0 + ((tid >> 6) << 4) + (tid & 15)) * Hd + ((tid >> 4) & 3) * 16;
  const char* bsrc2 = bplane + (size_t)blockIdx.y * NKB * 1024 + (size_t)lane * 16;
  i32x4 acc[3][8] = {};                // [plane][t], i32 exact (scaled by 2^t / -2^7)

  auto stage = [&](int kb, int buf) {
    gload_lds16(asrc + kb * 64, &lA[buf][tid * 16]);
    if (wave < 3)                      // 3 planes x 64 lanes; wave 3 stages A only
      gload_lds16(bsrc2 + (size_t)kb * 1024, &lB[buf][wave * 1024 + lane * 16]);
  };
  stage(0, 0); stage(1, 1);

#pragma unroll
  for (int kb = 0; kb < NKB; ++kb) {
    const int cur = kb % 3;
    if (kb < NKB - 1) {                // stage(kb) is 2 iters old -> free wait
      if (wave < 3) asm volatile("s_waitcnt vmcnt(2)" ::: "memory");
      else          asm volatile("s_waitcnt vmcnt(1)" ::: "memory");
    } else {
      asm volatile("s_waitcnt vmcnt(0)" ::: "memory");
    }
    __builtin_amdgcn_s_barrier();
    asm volatile("" ::: "memory");     // no LDS ops cross the barrier
    u32x4 ad = *(const u32x4*)&lA[cur][wave * 1024 + lane * 16];
    i32x4 fb0 = *(const i32x4*)&lB[cur][lane * 16];
    i32x4 fb1 = *(const i32x4*)&lB[cur][1024 + lane * 16];
    i32x4 fb2 = *(const i32x4*)&lB[cur][2048 + lane * 16];
    if (kb + 2 < NKB) stage(kb + 2, (kb + 2) % 3);
#pragma unroll
    for (int t = 0; t < 8; ++t) {      // masked expansion: A bytes {0, 2^t}
      const unsigned msk = 0x01010101u << t;
      i32x4 af;
      af[0] = (int)(ad[0] & msk);
      af[1] = (int)(ad[1] & msk);
      af[2] = (int)(ad[2] & msk);
      af[3] = (int)(ad[3] & msk);
      acc[0][t] = __builtin_amdgcn_mfma_i32_16x16x64_i8(af, fb0, acc[0][t], 0, 0, 0);
      acc[1][t] = __builtin_amdgcn_mfma_i32_16x16x64_i8(af, fb1, acc[1][t], 0, 0, 0);
      acc[2][t] = __builtin_amdgcn_mfma_i32_16x16x64_i8(af, fb2, acc[2][t], 0, 0, 0);
    }
  }
  // epilogue: exact i32 plane combine + full 8-step v2 recurrence
  const int n = n0 + l15;
  const float bb = b2[n];
#pragma unroll
  for (int r = 0; r < 4; ++r) {
    int m = m0 + wave * 16 + quad * 4 + r;
    size_t idx = (size_t)m * Hd + n;
    float v = 0.0f;
    unsigned bits = 0;
#pragma unroll
    for (int t = 0; t < 8; ++t) {
      int a0 = acc[0][t][r] >> t;      // exact: acc is 2^t * sum (t=7: -2^7 * sum)
      int a1 = acc[1][t][r] >> t;
      int a2 = acc[2][t][r] >> t;
      int s = (a0 << 14) + (a1 << 7) + a2;   // |s| <= 1.48e9 < 2^31
      float G = (float)s * ((t == 7) ? -CSCALE : CSCALE);
      float h = __fadd_rn(__fadd_rn(v, G), bb);  // np: (v2 + G) + b2
      if (__builtin_expect(__builtin_fabsf(h - 1.0f) < DELTA, 0)) {
        unsigned pos = atomicAdd(wcnt, 1u);      // fixup rewrites ALL 8 bits
        if (pos < WCAP) wlist[pos] = (unsigned)idx;
      }
      bool sp = (h >= 1.0f);
      if (sp) bits |= (1u << t);
      v = sp ? 0.0f : h;
    }
    s2p[idx] = (unsigned char)bits;
  }
}

// ---- fixup: replay np's v2 recursion for worklist sites (3 lanes/site, one
// per KC block; branchless ascending adds; np fold (S1+S2)+S3) — validated.
__global__ __launch_bounds__(256)
void fixup_kernel(const unsigned* __restrict__ wcnt, const unsigned* __restrict__ wlist,
                  const unsigned char* __restrict__ s1pack, const float* __restrict__ w2tf,
                  const float* __restrict__ b2, unsigned char* __restrict__ s2p) {
  unsigned cnt = *wcnt;
  if (cnt > WCAP) cnt = WCAP;
  const int tid = threadIdx.x;
  const int lane = tid & 63;
  const int sl = lane / 3, blk3 = lane - sl * 3;
  const int wid = blockIdx.x * (blockDim.x >> 6) + (tid >> 6);
  const int nwaves = gridDim.x * (blockDim.x >> 6);
  for (unsigned base = (unsigned)wid * 21u; base < cnt; base += (unsigned)nwaves * 21u) {
    unsigned site = base + (unsigned)sl;
    bool act = (sl < 21) && (site < cnt);
    unsigned idx = act ? wlist[site] : 0u;
    int m = (int)(idx >> 10), n = (int)(idx & 1023u);
    const unsigned char* prow = s1pack + ((size_t)m << 10);
    const float* col = w2tf + ((size_t)n << 10);
    int kb = blk3 * KC;
    int kend = (blk3 == 2) ? Hd : kb + KC;
    float S[8] = {};
    if (act) {
      for (int k = kb; k < kend; k += 8) {
        float4 wa = *(const float4*)(col + k);
        float4 wb = *(const float4*)(col + k + 4);
        unsigned b0 = *(const unsigned*)(prow + k);
        unsigned b1 = *(const unsigned*)(prow + k + 4);
#pragma unroll
        for (int tau = 0; tau < 8; ++tau) {
          S[tau] = __fadd_rn(S[tau], ((b0 >> tau) & 1)        ? wa.x : 0.0f);
          S[tau] = __fadd_rn(S[tau], ((b0 >> (8 + tau)) & 1)  ? wa.y : 0.0f);
          S[tau] = __fadd_rn(S[tau], ((b0 >> (16 + tau)) & 1) ? wa.z : 0.0f);
          S[tau] = __fadd_rn(S[tau], ((b0 >> (24 + tau)) & 1) ? wa.w : 0.0f);
          S[tau] = __fadd_rn(S[tau], ((b1 >> tau) & 1)        ? wb.x : 0.0f);
          S[tau] = __fadd_rn(S[tau], ((b1 >> (8 + tau)) & 1)  ? wb.y : 0.0f);
          S[tau] = __fadd_rn(S[tau], ((b1 >> (16 + tau)) & 1) ? wb.z : 0.0f);
          S[tau] = __fadd_rn(S[tau], ((b1 >> (24 + tau)) & 1) ? wb.w : 0.0f);
        }
      }
    }
    float G[8];
#pragma unroll
    for (int tau = 0; tau < 8; ++tau) {
      float sB = __shfl(S[tau], lane + 1);
      float sC = __shfl(S[tau], lane + 2);
      G[tau] = __fadd_rn(__fadd_rn(S[tau], sB), sC);
    }
    if (act && blk3 == 0) {
      float bb = b2[n];
      float v = 0.0f;
      unsigned bits = 0;
      for (int tau = 0; tau < 8; ++tau) {
        float h = __fadd_rn(__fadd_rn(v, G[tau]), bb);
        bool sp = (h >= 1.0f);
        if (sp) bits |= (1u << tau);
        v = sp ? 0.0f : h;
      }
      s2p[idx] = (unsigned char)bits;
    }
  }
}

// ======================================================================
// GEMM3 + FINAL fused (R11/R12-validated). Untouched.
// ======================================================================
__global__ __launch_bounds__(256, 3)
void gemm3f_kernel(const unsigned char* __restrict__ s2p,
                   const char* __restrict__ q1, const char* __restrict__ q2,
                   const char* __restrict__ q3,
                   const float* __restrict__ b3, const float* __restrict__ eps,
                   float* __restrict__ action, float* __restrict__ logp) {
  constexpr int NKB = Hd / 64;
  __shared__ float sv[16][65];
  const int tid = threadIdx.x;
  const int m0 = blockIdx.x * 16;
  const int wave = tid >> 6, lane = tid & 63, l15 = lane & 15, quad = lane >> 4;
  const unsigned char* asrc = s2p + (size_t)(m0 + l15) * Hd + (lane >> 4) * 16;
  const size_t boff = (size_t)wave * NKB * 1024 + (size_t)lane * 16;
  const char* bp0 = q1 + boff;
  const char* bp1 = q2 + boff;
  const char* bp2 = q3 + boff;
  i32x4 acc[3][8] = {};

  u32x4 a_cur = *(const u32x4*)asrc;
  i32x4 f0c = *(const i32x4*)bp0;
  i32x4 f1c = *(const i32x4*)bp1;
  i32x4 f2c = *(const i32x4*)bp2;
#pragma unroll
  for (int kb = 0; kb < NKB; ++kb) {
    u32x4 a_nxt = a_cur; i32x4 f0n = f0c, f1n = f1c, f2n = f2c;
    if (kb + 1 < NKB) {
      a_nxt = *(const u32x4*)(asrc + (kb + 1) * 64);
      f0n = *(const i32x4*)(bp0 + (size_t)(kb + 1) * 1024);
      f1n = *(const i32x4*)(bp1 + (size_t)(kb + 1) * 1024);
      f2n = *(const i32x4*)(bp2 + (size_t)(kb + 1) * 1024);
    }
#pragma unroll
    for (int t = 0; t < 8; ++t) {
      const unsigned msk = 0x01010101u << t;
      i32x4 af;
      af[0] = (int)(a_cur[0] & msk);
      af[1] = (int)(a_cur[1] & msk);
      af[2] = (int)(a_cur[2] & msk);
      af[3] = (int)(a_cur[3] & msk);
      acc[0][t] = __builtin_amdgcn_mfma_i32_16x16x64_i8(af, f0c, acc[0][t], 0, 0, 0);
      acc[1][t] = __builtin_amdgcn_mfma_i32_16x16x64_i8(af, f1c, acc[1][t], 0, 0, 0);
      acc[2][t] = __builtin_amdgcn_mfma_i32_16x16x64_i8(af, f2c, acc[2][t], 0, 0, 0);
    }
    a_cur = a_nxt; f0c = f0n; f1c = f1n; f2c = f2n;
  }
  // LIF v3 epilogue -> LDS tile (i32 combine, rounding-identical)
  const int n = wave * 16 + l15;       // 0..63
  const float bb = b3[n];
#pragma unroll
  for (int r = 0; r < 4; ++r) {
    int row = quad * 4 + r;            // 0..15
    float v = 0.0f;
#pragma unroll
    for (int t = 0; t < 8; ++t) {
      int a0 = acc[0][t][r] >> t;
      int a1 = acc[1][t][r] >> t;
      int a2 = acc[2][t][r] >> t;
      int s = (a0 << 14) + (a1 << 7) + a2;
      float ge = (float)s * ((t == 7) ? -CSCALE : CSCALE);
      float x3 = __fadd_rn(ge, bb);           // same op order as validated
      float dd = __fsub_rn(x3, v);
      v = __fadd_rn(v, __fmul_rn(dd, 0.5f));
    }
    sv[row][n] = v;
  }
  __syncthreads();
  // final math (identical fp32/double sequence as validated final_kernel)
#pragma unroll
  for (int pass = 0; pass < 2; ++pass) {
    int row = (pass << 3) + (tid >> 5);  // 0..15
    int j = tid & 31;
    float mu = sv[row][j];
    float ls = sv[row][32 + j];
    ls = fminf(fmaxf(ls, -20.0f), 2.0f);
    float sd = (float)exp((double)ls);
    float e  = eps[(size_t)(m0 + row) * Aact + j];
    float z  = __fadd_rn(mu, __fmul_rn(sd, e));
    float a;
    if (__builtin_fabsf(z) >= 7.90531111f) a = __builtin_copysignf(1.0f, z);
    else                                   a = (float)tanh((double)z);
    float aa = __fmul_rn(a, a);
    float u  = __fadd_rn(__fsub_rn(1.0f, aa), 1e-7f);
    float lg = (float)log((double)u);
    float l  = __fmul_rn(__fmul_rn(-0.5f, e), e);
    l = __fsub_rn(l, ls);
    l = __fsub_rn(l, 0.9189385332046727f);
    float term = __fsub_rn(l, lg);
    action[(size_t)(m0 + row) * Aact + j] = a;
    double lp = (double)term;
#pragma unroll
    for (int w = 16; w >= 1; w >>= 1) lp += __shfl_xor(lp, w);
    if (j == 0) logp[m0 + row] = (float)lp;
  }
}

extern "C" void kernel_launch(void* const* d_in, const int* in_sizes, int n_in,
                              void* d_out, int out_size, void* d_ws, size_t ws_size,
                              hipStream_t stream) {
  const float* state = (const float*)d_in[0];
  const float* w1 = (const float*)d_in[1];
  const float* b1 = (const float*)d_in[2];
  const float* w2 = (const float*)d_in[3];
  const float* b2 = (const float*)d_in[4];
  const float* w3 = (const float*)d_in[5];
  const float* b3 = (const float*)d_in[6];
  const float* eps = (const float*)d_in[7];
  float* out_action = (float*)d_out;
  float* out_logp = out_action + (size_t)Bsz * Aact;

  char* p = (char*)d_ws;
  auto take = [&](size_t bytes) {
    char* r = p;
    p += (bytes + 255) & ~(size_t)255;
    return r;
  };
  unsigned char* s1pack = (unsigned char*)take((size_t)Bsz * Hd);  // 8 MB
  unsigned char* s2p = (unsigned char*)take((size_t)Bsz * Hd);     // 8 MB (bit-packed)
  char* w2q1 = (char*)take((size_t)Hd * Hd);                       // 1 MB x3 i8 planes
  char* w2q2 = (char*)take((size_t)Hd * Hd);
  char* w2q3 = (char*)take((size_t)Hd * Hd);
  char* w3q1 = (char*)take((size_t)Hd * Od);                       // 64 KB x3
  char* w3q2 = (char*)take((size_t)Hd * Od);
  char* w3q3 = (char*)take((size_t)Hd * Od);
  float* w2tf = (float*)take((size_t)Hd * Hd * 4);                 // 4 MB
  unsigned* wcnt = (unsigned*)take(8 * 4);
  unsigned* wlist = (unsigned*)take((size_t)WCAP * 4);             // 1 MB

  prep_kernel<<<2048 + 272, 256, 0, stream>>>(state, w1, b1, w2, w3, s1pack,
                                              w2q1, w2q2, w2q3, w3q1, w3q2, w3q3,
                                              w2tf, wcnt);
  gemm2i8_kernel<<<dim3(Bsz / 64, Hd / 16), 256, 0, stream>>>(s1pack, w2q1, w2q2, w2q3,
                                                              b2, s2p, wcnt, wlist);
  fixup_kernel<<<256, 256, 0, stream>>>(wcnt, wlist, s1pack, w2tf, b2, s2p);

  gemm3f_kernel<<<Bsz / 16, 256, 0, stream>>>(s2p, w3q1, w3q2, w3q3, b3, eps,
                                              out_action, out_logp);
}